// Round 6
// baseline (52.209 us; speedup 1.0000x reference)
//
#include <hip/hip_runtime.h>
#include <math.h>

#define HH 96
#define WW 96
#define NPIX (HH*WW)          // 9216
#define CC 320
#define GG 32
#define CPG 10                // channels per group
#define TPB 512               // 8 waves; thread = (sextet r=tid>>5, xcl=tid&31)

typedef _Float16 half4v __attribute__((ext_vector_type(4)));

// ---------------------------------------------------------------------------
// Kernel 1 (single pass over x): one block per (b, group), all 96 rows.
// Thread (r, xcl) owns the row SEXTET Y = 6r..6r+5, pixels [xcl*4, xcl*4+4).
// Per channel: 8 float4 row loads (rows 6r-1 .. 6r+6, clamped+masked) cover
// all 6 output rows (1.33x L1 duplication vs 2x for pairs); halo px via wave
// shfl (2 per loaded row = 16); 3x3 conv for 24 px, accumulating
//   p[j]   += (proj_w*gn_w)[c] * u             (stats-independent plane)
//   s1,s2  += h, h^2   with h = u + dw_b[c]    (GN statistics)
// P stored once at the end as fp16 (logit error ~1e-5 vs 0.02 budget).
// ---------------------------------------------------------------------------
__global__ __launch_bounds__(TPB, 4)   // cap VGPR at 128 -> 16 waves/CU
void k_main(const float* __restrict__ x, const float* __restrict__ dw_w,
            const float* __restrict__ dw_b, const float* __restrict__ gn_w,
            const float* __restrict__ proj_w,
            _Float16* __restrict__ P, float* __restrict__ partials) {
  const int gr = blockIdx.x & 31;
  const int b  = blockIdx.x >> 5;

  __shared__ float wsm[CPG * 9], ssm[CPG], bsm[CPG];
  const int tid = threadIdx.x;
  if (tid < CPG * 9) wsm[tid] = dw_w[gr * CPG * 9 + tid];
  if (tid < CPG) {
    int c = gr * CPG + tid;
    ssm[tid] = proj_w[c] * gn_w[c];
    bsm[tid] = dw_b[c];
  }
  __syncthreads();

  const int lane = tid & 63;
  const int xcl  = tid & 31;            // 0..31; active if <24
  const int r    = tid >> 5;            // sextet index 0..15 -> rows 6r..6r+5
  const bool active = xcl < 24;
  const float mact  = active ? 1.f : 0.f;
  const int xc = min(xcl, 23);          // clamp inactive lanes to safe addr
  const float mlft = (xcl > 0)  ? 1.f : 0.f;
  const float mrgt = (xcl < 23) ? 1.f : 0.f;
  const int lm1 = (xcl >= 1) ? lane - 1 : lane;   // stays within 32-lane row
  const int lp1 = (xcl < 31) ? lane + 1 : lane;

  const float mtop = (r > 0)  ? 1.f : 0.f;   // row 6r-1 exists
  const float mbot = (r < 15) ? 1.f : 0.f;   // row 6r+6 exists

  int offs[8];
  #pragma unroll
  for (int k = 0; k < 8; ++k) {
    int yy = min(max(6 * r - 1 + k, 0), HH - 1);
    offs[k] = yy * WW + xc * 4;
  }
  const float* xg = x + ((size_t)(b * CC + gr * CPG)) * NPIX;

  float p[24];
  #pragma unroll
  for (int i = 0; i < 24; ++i) p[i] = 0.f;
  float s1 = 0.f, s2 = 0.f;

  #pragma unroll 1
  for (int ch = 0; ch < CPG; ++ch) {
    const float* img = xg + ch * NPIX;

    // 8 row loads issued together (MLP), then masked
    float4 R[8];
    #pragma unroll
    for (int k = 0; k < 8; ++k) R[k] = *(const float4*)(img + offs[k]);
    R[0].x *= mtop; R[0].y *= mtop; R[0].z *= mtop; R[0].w *= mtop;
    R[7].x *= mbot; R[7].y *= mbot; R[7].z *= mbot; R[7].w *= mbot;

    // halo pixels from wave neighbors: 2 shfl per loaded row
    float L[8], T[8];
    #pragma unroll
    for (int k = 0; k < 8; ++k) {
      L[k] = __shfl(R[k].w, lm1) * mlft;
      T[k] = __shfl(R[k].x, lp1) * mrgt;
    }

    const float* wp = &wsm[ch * 9];
    const float w0 = wp[0], w1 = wp[1], w2 = wp[2];
    const float w3 = wp[3], w4 = wp[4], w5 = wp[5];
    const float w6 = wp[6], w7 = wp[7], w8 = wp[8];
    const float sc = ssm[ch], bias = bsm[ch];

    #pragma unroll
    for (int j = 0; j < 6; ++j) {       // output row 6r+j uses R[j],R[j+1],R[j+2]
      const float4 A = R[j], B = R[j + 1], C = R[j + 2];
      const float la = L[j], lb = L[j + 1], lc = L[j + 2];
      const float ta = T[j], tb = T[j + 1], tc = T[j + 2];

      float u0 = w0*la  + w1*A.x + w2*A.y + w3*lb  + w4*B.x + w5*B.y + w6*lc  + w7*C.x + w8*C.y;
      float u1 = w0*A.x + w1*A.y + w2*A.z + w3*B.x + w4*B.y + w5*B.z + w6*C.x + w7*C.y + w8*C.z;
      float u2 = w0*A.y + w1*A.z + w2*A.w + w3*B.y + w4*B.z + w5*B.w + w6*C.y + w7*C.z + w8*C.w;
      float u3 = w0*A.z + w1*A.w + w2*ta  + w3*B.z + w4*B.w + w5*tb  + w6*C.z + w7*C.w + w8*tc;

      p[j*4+0] = fmaf(sc, u0, p[j*4+0]);
      p[j*4+1] = fmaf(sc, u1, p[j*4+1]);
      p[j*4+2] = fmaf(sc, u2, p[j*4+2]);
      p[j*4+3] = fmaf(sc, u3, p[j*4+3]);

      float h0 = u0 + bias, h1 = u1 + bias, h2 = u2 + bias, h3 = u3 + bias;
      s1 += mact * ((h0 + h1) + (h2 + h3));
      s2 += mact * (fmaf(h0, h0, h1 * h1) + fmaf(h2, h2, h3 * h3));
    }
  }

  if (active) {
    _Float16* Pp = P + ((size_t)(b * GG + gr)) * NPIX;
    #pragma unroll
    for (int j = 0; j < 6; ++j) {
      half4v h;
      h.x = (_Float16)p[j*4+0]; h.y = (_Float16)p[j*4+1];
      h.z = (_Float16)p[j*4+2]; h.w = (_Float16)p[j*4+3];
      *(half4v*)&Pp[(size_t)(6 * r + j) * WW + xcl * 4] = h;
    }
  }

  // block-reduce s1,s2 (8 waves)
  #pragma unroll
  for (int off = 32; off; off >>= 1) {
    s1 += __shfl_down(s1, off);
    s2 += __shfl_down(s2, off);
  }
  __shared__ float r1[8], r2[8];
  if ((tid & 63) == 0) { r1[tid >> 6] = s1; r2[tid >> 6] = s2; }
  __syncthreads();
  if (tid == 0) {
    float a = 0.f, q = 0.f;
    #pragma unroll
    for (int i = 0; i < 8; ++i) { a += r1[i]; q += r2[i]; }
    partials[blockIdx.x * 2]     = a;
    partials[blockIdx.x * 2 + 1] = q;
  }
}

// ---------------------------------------------------------------------------
// Kernel 2: fused coef + output. Each block (18 per batch) recomputes its
// batch's 32 rinv values + scalar D from partials, then
// out[b,p] = sigmoid( sum_g rinv[g]*P[b,g,p] + D ).  128 thr, 4 px/thread.
// ---------------------------------------------------------------------------
__global__ __launch_bounds__(128)
void k_out(const _Float16* __restrict__ P, const float* __restrict__ partials,
           const float* __restrict__ dw_b, const float* __restrict__ gn_w,
           const float* __restrict__ gn_b, const float* __restrict__ proj_w,
           const float* __restrict__ proj_b, float* __restrict__ out) {
  const int b   = blockIdx.x / 18;
  const int blk = blockIdx.x % 18;
  __shared__ float rs[GG];
  __shared__ float Ds;

  if (threadIdx.x < GG) {
    const int gr = threadIdx.x;
    float s1 = partials[(b * GG + gr) * 2];
    float s2 = partials[(b * GG + gr) * 2 + 1];
    const float invN = 1.f / (float)(CPG * NPIX);
    float mean = s1 * invN;
    float var  = s2 * invN - mean * mean;
    float rinv = rsqrtf(var + 1e-5f);
    rs[gr] = rinv;
    float K = 0.f, E = 0.f;
    #pragma unroll
    for (int i = 0; i < CPG; ++i) {
      int c = gr * CPG + i;
      float pg = proj_w[c] * gn_w[c];
      K = fmaf(pg, dw_b[c] - mean, K);
      E = fmaf(proj_w[c], gn_b[c], E);
    }
    float contrib = fmaf(rinv, K, E);
    #pragma unroll
    for (int m = 16; m; m >>= 1) contrib += __shfl_xor(contrib, m, 32);
    if (gr == 0) Ds = contrib + proj_b[0];
  }
  __syncthreads();

  const int p = (blk * 128 + threadIdx.x) * 4;    // 18*128*4 = 9216
  const _Float16* Pb = P + (size_t)b * GG * NPIX + p;
  float g0 = 0.f, g1 = 0.f, g2 = 0.f, g3 = 0.f;
  #pragma unroll
  for (int gr = 0; gr < GG; ++gr) {
    half4v v = *(const half4v*)(Pb + (size_t)gr * NPIX);
    float rr = rs[gr];
    g0 = fmaf(rr, (float)v.x, g0);
    g1 = fmaf(rr, (float)v.y, g1);
    g2 = fmaf(rr, (float)v.z, g2);
    g3 = fmaf(rr, (float)v.w, g3);
  }
  const float d = Ds;
  float4 o;
  o.x = 1.f / (1.f + expf(-(g0 + d)));
  o.y = 1.f / (1.f + expf(-(g1 + d)));
  o.z = 1.f / (1.f + expf(-(g2 + d)));
  o.w = 1.f / (1.f + expf(-(g3 + d)));
  *(float4*)&out[(size_t)b * NPIX + p] = o;
}

// ---------------------------------------------------------------------------
extern "C" void kernel_launch(void* const* d_in, const int* in_sizes, int n_in,
                              void* d_out, int out_size, void* d_ws, size_t ws_size,
                              hipStream_t stream) {
  const float* x      = (const float*)d_in[0];
  const float* dw_w   = (const float*)d_in[1];
  const float* dw_b   = (const float*)d_in[2];
  const float* gn_w   = (const float*)d_in[3];
  const float* gn_b   = (const float*)d_in[4];
  const float* proj_w = (const float*)d_in[5];
  const float* proj_b = (const float*)d_in[6];
  float* out = (float*)d_out;

  const size_t P_BYTES = (size_t)16 * GG * NPIX * 2;     // fp16: 9,437,184 B
  _Float16* P     = (_Float16*)d_ws;
  float* partials = (float*)((char*)d_ws + P_BYTES);     // 512*2 f32

  hipLaunchKernelGGL(k_main, dim3(16 * GG), dim3(TPB), 0, stream,
                     x, dw_w, dw_b, gn_w, proj_w, P, partials);
  hipLaunchKernelGGL(k_out, dim3(16 * 18), dim3(128), 0, stream,
                     P, partials, dw_b, gn_w, gn_b, proj_w, proj_b, out);
}